// Round 7
// baseline (923.077 us; speedup 1.0000x reference)
//
#include <hip/hip_runtime.h>
#include <cmath>

typedef unsigned long long u64;

#define PRE_TOPN 12000
#define POST_TOPN 2000
#define SORTN 32768
#define TILE 8192
#define NTILE (SORTN / TILE)   // 4 tiles per batch
#define NBLK 188               // 64-bit column blocks covering 12032
#define PADN (NBLK * 64)       // 12032
// triangular bitmap: column-block cb stores rows 0..(cb+1)*64-1
// triOff(cb) = 32*cb*(cb+1); total words per batch:
#define TRI_WORDS (32 * (NBLK - 1) * NBLK + NBLK * 64)  // 1,137,024

__device__ inline u64 shfl_u64(u64 v, int lane) {
    int lo = __shfl((int)(unsigned)(v & 0xffffffffULL), lane);
    int hi = __shfl((int)(unsigned)(v >> 32), lane);
    return ((u64)(unsigned)hi << 32) | (u64)(unsigned)lo;
}

__device__ inline u64 shfl_xor_u64(u64 v, int mask) {
    int lo = __shfl_xor((int)(unsigned)(v & 0xffffffffULL), mask);
    int hi = __shfl_xor((int)(unsigned)(v >> 32), mask);
    return ((u64)(unsigned)hi << 32) | (u64)(unsigned)lo;
}

// ---------------------------------------------------------------------------
// Kernel 1: decode boxes (exact fp32 op order, no FMA contraction, exp via
// double) and pack sort keys. key = (~score_bits)<<32 | idx.
// ---------------------------------------------------------------------------
__global__ void decode_pack(const float* __restrict__ anchors,
                            const float* __restrict__ deltas,
                            const float* __restrict__ scores,
                            float* __restrict__ boxes,
                            u64* __restrict__ keys,
                            int N) {
#pragma clang fp contract(off)
    int n = blockIdx.x * blockDim.x + threadIdx.x;
    int b = blockIdx.y;
    if (n >= SORTN) return;
    u64* kb = keys + (size_t)b * SORTN;
    if (n < N) {
        float a0 = anchors[n * 4 + 0];
        float a1 = anchors[n * 4 + 1];
        float a2 = anchors[n * 4 + 2];
        float a3 = anchors[n * 4 + 3];
        float w = (a2 - a0) + 1.0f;
        float h = (a3 - a1) + 1.0f;
        float cx = a0 + 0.5f * w;
        float cy = a1 + 0.5f * h;
        const float* d = deltas + ((size_t)b * N + n) * 4;
        float dx = d[0], dy = d[1], dw = d[2], dh = d[3];
        float px = cx + w * dx;
        float py = cy + h * dy;
        float pw = (float)::exp((double)dw) * w;
        float ph = (float)::exp((double)dh) * h;
        float* bb = boxes + ((size_t)b * N + n) * 4;
        bb[0] = px - 0.5f * pw;
        bb[1] = py - 0.5f * ph;
        bb[2] = px + 0.5f * (pw - 2.0f);
        bb[3] = py + 0.5f * (ph - 2.0f);
        unsigned int sb = __float_as_uint(scores[(size_t)b * N + n]);
        kb[n] = ((u64)(~sb) << 32) | (u64)(unsigned int)n;
    } else {
        kb[n] = ~0ULL;
    }
}

// ---------------------------------------------------------------------------
// Hybrid bitonic sort (unchanged).
// ---------------------------------------------------------------------------
__global__ __launch_bounds__(1024) void bitonic_local_sort(u64* __restrict__ keys) {
    __shared__ u64 sk[TILE];
    int tile = blockIdx.x;
    u64* kb = keys + (size_t)tile * TILE;
    int base = (tile % NTILE) * TILE;
    for (int i = threadIdx.x; i < TILE; i += 1024) sk[i] = kb[i];
    __syncthreads();
    for (int k = 2; k <= TILE; k <<= 1) {
        for (int j = k >> 1; j > 0; j >>= 1) {
            for (int t = threadIdx.x; t < TILE / 2; t += 1024) {
                int i = ((t & ~(j - 1)) << 1) | (t & (j - 1));
                int ixj = i | j;
                u64 a = sk[i];
                u64 c = sk[ixj];
                bool up = (((base + i) & k) == 0);
                if ((a > c) == up) { sk[i] = c; sk[ixj] = a; }
            }
            __syncthreads();
        }
    }
    for (int i = threadIdx.x; i < TILE; i += 1024) kb[i] = sk[i];
}

__global__ void bitonic_global_step(u64* __restrict__ keys, int k, int j) {
    int t = blockIdx.x * blockDim.x + threadIdx.x;
    int b = t / (SORTN / 2);
    int s = t % (SORTN / 2);
    int i = ((s & ~(j - 1)) << 1) | (s & (j - 1));
    int ixj = i | j;
    u64* kb = keys + (size_t)b * SORTN;
    u64 a = kb[i];
    u64 c = kb[ixj];
    bool up = ((i & k) == 0);
    if ((a > c) == up) { kb[i] = c; kb[ixj] = a; }
}

__global__ __launch_bounds__(1024) void bitonic_local_merge(u64* __restrict__ keys, int k) {
    __shared__ u64 sk[TILE];
    int tile = blockIdx.x;
    u64* kb = keys + (size_t)tile * TILE;
    int base = (tile % NTILE) * TILE;
    bool up = ((base & k) == 0);
    for (int i = threadIdx.x; i < TILE; i += 1024) sk[i] = kb[i];
    __syncthreads();
    for (int j = TILE / 2; j > 0; j >>= 1) {
        for (int t = threadIdx.x; t < TILE / 2; t += 1024) {
            int i = ((t & ~(j - 1)) << 1) | (t & (j - 1));
            int ixj = i | j;
            u64 a = sk[i];
            u64 c = sk[ixj];
            if ((a > c) == up) { sk[i] = c; sk[ixj] = a; }
        }
        __syncthreads();
    }
    for (int i = threadIdx.x; i < TILE; i += 1024) kb[i] = sk[i];
}

// ---------------------------------------------------------------------------
// Gather sorted top-PADN boxes. Pad rows get far-away degenerate boxes.
// ---------------------------------------------------------------------------
__global__ void gather_sorted(const float* __restrict__ boxes,
                              const u64* __restrict__ keys,
                              float4* __restrict__ sbox, int N) {
    int r = blockIdx.x * 256 + threadIdx.x;
    int b = blockIdx.y;
    if (r >= PADN) return;
    float4 v;
    if (r < PRE_TOPN) {
        u64 key = keys[(size_t)b * SORTN + r];
        int n = (int)(unsigned)(key & 0xffffffffULL);
        v = ((const float4*)boxes)[(size_t)b * N + n];
    } else {
        v = make_float4(-4e8f, -4e8f, -4e8f, -4e8f);
    }
    sbox[(size_t)b * PADN + r] = v;
}

// ---------------------------------------------------------------------------
// FUSED build + scan. Grid (NBLK+1, 47, B), 256 threads.
//   blockIdx.x < NBLK : build role — identical IoU-bitmap math as round 6
//     (division-free exact predicate: RN_f32(inter/un) > 0.7f <=>
//      (double)inter >= MD*(double)un, MD = 0.7f + 2^-25, product exact in
//      f64). Bitmap words stored with agent-scope relaxed atomic stores
//      (coherent point, immune to cross-XCD L2 writeback timing); after
//      __syncthreads (drains vmcnt) tid0 does __threadfence + atomicAdd on
//      ready[b][cb].
//   blockIdx.x == NBLK && y == 0 : scan role for batch z — round-6 deferred-
//     OR scan, but before processing row-block rb it spin-waits until
//     ready[b][rb] == rb/4+1 (all build blocks of that slab done). Slab
//     reads use agent-scope relaxed atomic loads -> always fresh.
// Scan consumes slabs at ~0.7 us each while build produces ~27 slabs/us in
// roughly cb-ascending dispatch order -> scan hides entirely under build.
// Deadlock-free: <=8 spinning blocks, 35K build blocks, 256 CUs; no
// correctness dependence on dispatch order (spins tolerate any order).
// ---------------------------------------------------------------------------
__global__ __launch_bounds__(256) void fused_build_scan(const float4* __restrict__ sbox,
                                                        u64* __restrict__ bitmap,
                                                        int* __restrict__ ready,
                                                        float* __restrict__ out) {
#pragma clang fp contract(off)
    const double MD = (double)0.7f + 0x1p-25;   // exact midpoint multiplier
    int x = blockIdx.x;
    int chunk = blockIdx.y;
    int b = blockIdx.z;
    int tid = threadIdx.x;

    __shared__ float4 cbox[64];
    __shared__ float carea[64];
    __shared__ int picks_lds[POST_TOPN];   // scan role
    __shared__ u64 s_partial[4];
    __shared__ int s_K;

    if (x < NBLK) {
        // ---------------- build role ----------------
        int cb = x;
        if (chunk * 4 > cb) return;       // empty row-chunk for this slab
        const float4* sb = sbox + (size_t)b * PADN;
        if (tid < 64) {
            float4 c4 = sb[cb * 64 + tid];
            cbox[tid] = c4;
            carea[tid] = ((c4.z - c4.x) + 1.0f) * ((c4.w - c4.y) + 1.0f);
        }
        int r = chunk * 256 + tid;        // r <= 12031 < PADN, safe
        float4 me = sb[r];
        float ar = ((me.z - me.x) + 1.0f) * ((me.w - me.y) + 1.0f);
        __syncthreads();

        u64 word = 0;
#pragma unroll
        for (int j = 0; j < 64; ++j) {
            float4 cj = cbox[j];
            float aj = carea[j];
            float xx1 = fmaxf(me.x, cj.x);
            float yy1 = fmaxf(me.y, cj.y);
            float xx2 = fminf(me.z, cj.z);
            float yy2 = fminf(me.w, cj.w);
            float w = fmaxf((xx2 - xx1) + 1.0f, 0.0f);
            float h = fmaxf((yy2 - yy1) + 1.0f, 0.0f);
            float inter = w * h;
            float un = (ar + aj) - inter;
            bool sup = ((double)inter >= MD * (double)un);
            word |= ((u64)sup) << j;
        }
        int d = r - cb * 64;
        if (d >= 0) word &= ~((2ULL << d) - 1ULL);   // upper triangle only

        if (r < (cb + 1) * 64) {
            u64* dst = bitmap + (size_t)b * TRI_WORDS + (size_t)32 * cb * (cb + 1) + (size_t)r;
            __hip_atomic_store(dst, word, __ATOMIC_RELAXED, __HIP_MEMORY_SCOPE_AGENT);
        }
        __syncthreads();                   // waitcnt drains all stores
        if (tid == 0) {
            __threadfence();
            atomicAdd(&ready[b * NBLK + cb], 1);
        }
        return;
    }

    // ---------------- scan role ----------------
    if (chunk != 0) return;
    int lane = tid & 63;
    int wv = tid >> 6;
    if (tid == 0) s_K = 0;
    __syncthreads();

    u64* bm = bitmap + (size_t)b * TRI_WORDS;

    for (int rb = 0; rb < NBLK; ++rb) {
        int K = s_K;                       // uniform (previous-iteration barrier)
        if (K >= POST_TOPN) break;

        // wait for slab rb to be fully built
        if (tid == 0) {
            int need = rb / 4 + 1;
            while (__hip_atomic_load(&ready[b * NBLK + rb], __ATOMIC_RELAXED,
                                     __HIP_MEMORY_SCOPE_AGENT) < need) {
                __builtin_amdgcn_s_sleep(2);
            }
        }
        __syncthreads();

        u64* slab = bm + (size_t)32 * rb * (rb + 1);  // rows 0..(rb+1)*64-1
        int base = rb * 64;

        // wave-0 prefetch (issues before the gather's waits)
        u64 myrow = 0;
        float4 mybox = make_float4(0.f, 0.f, 0.f, 0.f);
        if (wv == 0) {
            myrow = __hip_atomic_load(&slab[base + lane], __ATOMIC_RELAXED,
                                      __HIP_MEMORY_SCOPE_AGENT);
            mybox = sbox[(size_t)b * PADN + base + lane];
        }

        // deferred gather: OR suppression words of all prior picks
        u64 sup = 0;
        {
            int t = tid;
            for (; t + 768 < K; t += 1024) {
                u64 w0 = __hip_atomic_load(&slab[picks_lds[t]],       __ATOMIC_RELAXED, __HIP_MEMORY_SCOPE_AGENT);
                u64 w1 = __hip_atomic_load(&slab[picks_lds[t + 256]], __ATOMIC_RELAXED, __HIP_MEMORY_SCOPE_AGENT);
                u64 w2 = __hip_atomic_load(&slab[picks_lds[t + 512]], __ATOMIC_RELAXED, __HIP_MEMORY_SCOPE_AGENT);
                u64 w3 = __hip_atomic_load(&slab[picks_lds[t + 768]], __ATOMIC_RELAXED, __HIP_MEMORY_SCOPE_AGENT);
                sup |= (w0 | w1) | (w2 | w3);
            }
            for (; t < K; t += 256)
                sup |= __hip_atomic_load(&slab[picks_lds[t]], __ATOMIC_RELAXED, __HIP_MEMORY_SCOPE_AGENT);
        }
        for (int off = 1; off < 64; off <<= 1) sup |= shfl_xor_u64(sup, off);
        if (lane == 0) s_partial[wv] = sup;
        __syncthreads();

        if (wv == 0) {
            u64 total = s_partial[0] | s_partial[1] | s_partial[2] | s_partial[3];
            if (rb == NBLK - 1) total |= 0xFFFFFFFF00000000ULL;   // pad rows >= 12000
            int c = lane;
            u64 alive = ~total;
            u64 picks = 0;
            u64 cur = alive;
            while (cur) {
                int i = __ffsll((long long)cur) - 1;
                picks |= 1ULL << i;
                u64 row = shfl_u64(myrow, i);
                alive &= ~row;
                cur = alive & ~((2ULL << i) - 1ULL);
            }
            int avail = POST_TOPN - K;
            int np = __popcll(picks);
            while (np > avail) {                       // truncate latest picks
                picks &= ~(1ULL << (63 - __clzll(picks)));
                --np;
            }
            if ((picks >> c) & 1ULL) {
                int rank = __popcll(picks & ((1ULL << c) - 1ULL));
                picks_lds[K + rank] = base + c;
                float* o = out + ((size_t)b * POST_TOPN + K + rank) * 5;
                o[0] = (float)b; o[1] = mybox.x; o[2] = mybox.y; o[3] = mybox.z; o[4] = mybox.w;
            }
            if (c == 0) s_K = K + np;
        }
        __syncthreads();
    }

    int K = s_K;
    for (int r = K + tid; r < POST_TOPN; r += 256) {
        float* o = out + ((size_t)b * POST_TOPN + r) * 5;
        o[0] = 0.0f; o[1] = 0.0f; o[2] = 0.0f; o[3] = 0.0f; o[4] = 0.0f;
    }
}

// ---------------------------------------------------------------------------
// Fallback (round-2) NMS kernel — used only if ws_size can't hold the bitmap.
// ---------------------------------------------------------------------------
__global__ __launch_bounds__(1024) void nms_kernel(const float* __restrict__ boxes,
                                                   const u64* __restrict__ keys,
                                                   float* __restrict__ out,
                                                   int N) {
#pragma clang fp contract(off)
    __shared__ float4 kbox[POST_TOPN];
    __shared__ float kar[POST_TOPN];
    __shared__ float4 cbox[64];
    __shared__ float car_s[64];
    __shared__ int supp[64];
    __shared__ int s_cnt;

    int b = blockIdx.x;
    int tid = threadIdx.x;
    const u64* kb = keys + (size_t)b * SORTN;
    const float* bb = boxes + (size_t)b * N * 4;

    if (tid == 0) s_cnt = 0;
    __syncthreads();

    for (int start = 0; start < PRE_TOPN; start += 64) {
        int K = s_cnt;
        if (K >= POST_TOPN) break;
        int csize = min(64, PRE_TOPN - start);

        if (tid < 64) {
            int c = tid;
            if (c < csize) {
                u64 key = kb[start + c];
                int n = (int)(unsigned int)(key & 0xFFFFFFFFULL);
                const float* p = bb + (size_t)n * 4;
                float x1 = p[0], y1 = p[1], x2 = p[2], y2 = p[3];
                cbox[c] = make_float4(x1, y1, x2, y2);
                car_s[c] = ((x2 - x1) + 1.0f) * ((y2 - y1) + 1.0f);
            }
            supp[c] = 0;
        }
        __syncthreads();

        {
            int c = tid & 63;
            int sl = tid >> 6;
            if (c < csize) {
                float4 me = cbox[c];
                float ar = car_s[c];
                int flag = 0;
                for (int kk = sl; kk < K; kk += 16) {
                    float4 k0 = kbox[kk];
                    float a0 = kar[kk];
                    float xx1 = fmaxf(k0.x, me.x);
                    float yy1 = fmaxf(k0.y, me.y);
                    float xx2 = fminf(k0.z, me.z);
                    float yy2 = fminf(k0.w, me.w);
                    float w0 = fmaxf((xx2 - xx1) + 1.0f, 0.0f);
                    float h0 = fmaxf((yy2 - yy1) + 1.0f, 0.0f);
                    float inter0 = w0 * h0;
                    float iou0 = inter0 / ((a0 + ar) - inter0);
                    if (iou0 > 0.7f) { flag = 1; break; }
                }
                if (flag) supp[c] = 1;
            }
        }
        __syncthreads();

        if (tid < 64) {
            int c = tid;
            bool alive = (c < csize) && (supp[c] == 0);
            float4 me = cbox[c];
            float ar = car_s[c];
            int cnt = K;
            u64 m = __ballot(alive);
            while (m != 0 && cnt < POST_TOPN) {
                int i = __ffsll((unsigned long long)m) - 1;
                float ix1 = __shfl(me.x, i);
                float iy1 = __shfl(me.y, i);
                float ix2 = __shfl(me.z, i);
                float iy2 = __shfl(me.w, i);
                float iar = __shfl(ar, i);
                if (c == i) {
                    kbox[cnt] = me;
                    kar[cnt] = ar;
                    float* o = out + ((size_t)b * POST_TOPN + cnt) * 5;
                    o[0] = (float)b; o[1] = me.x; o[2] = me.y; o[3] = me.z; o[4] = me.w;
                }
                if (alive && c > i) {
                    float xx1 = fmaxf(ix1, me.x);
                    float yy1 = fmaxf(iy1, me.y);
                    float xx2 = fminf(ix2, me.z);
                    float yy2 = fminf(iy2, me.w);
                    float w = fmaxf((xx2 - xx1) + 1.0f, 0.0f);
                    float h = fmaxf((yy2 - yy1) + 1.0f, 0.0f);
                    float inter = w * h;
                    float iou = inter / ((iar + ar) - inter);
                    if (iou > 0.7f) alive = false;
                }
                cnt++;
                m = __ballot(alive);
                u64 clearmask = (2ULL << i) - 1ULL;
                m &= ~clearmask;
            }
            if (c == 0) s_cnt = cnt;
        }
        __syncthreads();
    }

    __syncthreads();
    int K = s_cnt;
    for (int r = K + tid; r < POST_TOPN; r += (int)blockDim.x) {
        float* o = out + ((size_t)b * POST_TOPN + r) * 5;
        o[0] = 0.0f; o[1] = 0.0f; o[2] = 0.0f; o[3] = 0.0f; o[4] = 0.0f;
    }
}

// ---------------------------------------------------------------------------
extern "C" void kernel_launch(void* const* d_in, const int* in_sizes, int n_in,
                              void* d_out, int out_size, void* d_ws, size_t ws_size,
                              hipStream_t stream) {
    const float* anchors = (const float*)d_in[0];
    const float* deltas  = (const float*)d_in[1];
    const float* scores  = (const float*)d_in[2];
    float* out = (float*)d_out;

    int N = in_sizes[0] / 4;           // 27380
    int B = in_sizes[2] / N;           // 8

    size_t off = 0;
    auto take = [&](size_t bytes) { size_t o = off; off = (off + bytes + 255) & ~(size_t)255; return o; };
    size_t boxesOff  = take((size_t)B * N * 4 * sizeof(float));
    size_t keysOff   = take((size_t)B * SORTN * sizeof(u64));
    size_t sboxOff   = take((size_t)B * PADN * sizeof(float4));
    size_t readyOff  = take((size_t)B * NBLK * sizeof(int));
    size_t bitmapOff = take((size_t)B * TRI_WORDS * sizeof(u64));
    bool bitmap_path = (off <= ws_size);

    float* boxes = (float*)((char*)d_ws + boxesOff);
    u64*   keys  = (u64*)((char*)d_ws + keysOff);

    dim3 g1((unsigned)((SORTN + 255) / 256), (unsigned)B);
    decode_pack<<<g1, 256, 0, stream>>>(anchors, deltas, scores, boxes, keys, N);

    int ntiles = B * NTILE;
    bitonic_local_sort<<<ntiles, 1024, 0, stream>>>(keys);
    int gsteps = B * (SORTN / 2) / 256;
    bitonic_global_step<<<gsteps, 256, 0, stream>>>(keys, 2 * TILE, TILE);
    bitonic_local_merge<<<ntiles, 1024, 0, stream>>>(keys, 2 * TILE);
    bitonic_global_step<<<gsteps, 256, 0, stream>>>(keys, 4 * TILE, 2 * TILE);
    bitonic_global_step<<<gsteps, 256, 0, stream>>>(keys, 4 * TILE, TILE);
    bitonic_local_merge<<<ntiles, 1024, 0, stream>>>(keys, 4 * TILE);

    if (bitmap_path) {
        float4* sbox = (float4*)((char*)d_ws + sboxOff);
        u64* bitmap  = (u64*)((char*)d_ws + bitmapOff);
        int* ready   = (int*)((char*)d_ws + readyOff);
        dim3 gg((unsigned)((PADN + 255) / 256), (unsigned)B);
        gather_sorted<<<gg, 256, 0, stream>>>(boxes, keys, sbox, N);
        hipMemsetAsync(ready, 0, (size_t)B * NBLK * sizeof(int), stream);
        dim3 gb((unsigned)(NBLK + 1), 47u, (unsigned)B);
        fused_build_scan<<<gb, 256, 0, stream>>>(sbox, bitmap, ready, out);
    } else {
        nms_kernel<<<B, 1024, 0, stream>>>(boxes, keys, out, N);
    }
}

// Round 8
// 841.870 us; speedup vs baseline: 1.0965x; 1.0965x over previous
//
#include <hip/hip_runtime.h>
#include <cmath>

typedef unsigned long long u64;

#define PRE_TOPN 12000
#define POST_TOPN 2000
#define SORTN 32768
#define TILE 8192
#define NTILE (SORTN / TILE)   // 4 tiles per batch
#define NBLK 188               // 64-bit column blocks covering 12032
#define PADN (NBLK * 64)       // 12032
// triangular bitmap: column-block cb stores rows 0..(cb+1)*64-1
// triOff(cb) = 32*cb*(cb+1); total words per batch:
#define TRI_WORDS (32 * (NBLK - 1) * NBLK + NBLK * 64)  // 1,137,024

__device__ inline u64 shfl_u64(u64 v, int lane) {
    int lo = __shfl((int)(unsigned)(v & 0xffffffffULL), lane);
    int hi = __shfl((int)(unsigned)(v >> 32), lane);
    return ((u64)(unsigned)hi << 32) | (u64)(unsigned)lo;
}

__device__ inline u64 shfl_xor_u64(u64 v, int mask) {
    int lo = __shfl_xor((int)(unsigned)(v & 0xffffffffULL), mask);
    int hi = __shfl_xor((int)(unsigned)(v >> 32), mask);
    return ((u64)(unsigned)hi << 32) | (u64)(unsigned)lo;
}

// ---------------------------------------------------------------------------
// Kernel 1: decode boxes (exact fp32 op order, no FMA contraction, exp via
// double) and pack sort keys. key = (~score_bits)<<32 | idx.
// ---------------------------------------------------------------------------
__global__ void decode_pack(const float* __restrict__ anchors,
                            const float* __restrict__ deltas,
                            const float* __restrict__ scores,
                            float* __restrict__ boxes,
                            u64* __restrict__ keys,
                            int N) {
#pragma clang fp contract(off)
    int n = blockIdx.x * blockDim.x + threadIdx.x;
    int b = blockIdx.y;
    if (n >= SORTN) return;
    u64* kb = keys + (size_t)b * SORTN;
    if (n < N) {
        float a0 = anchors[n * 4 + 0];
        float a1 = anchors[n * 4 + 1];
        float a2 = anchors[n * 4 + 2];
        float a3 = anchors[n * 4 + 3];
        float w = (a2 - a0) + 1.0f;
        float h = (a3 - a1) + 1.0f;
        float cx = a0 + 0.5f * w;
        float cy = a1 + 0.5f * h;
        const float* d = deltas + ((size_t)b * N + n) * 4;
        float dx = d[0], dy = d[1], dw = d[2], dh = d[3];
        float px = cx + w * dx;
        float py = cy + h * dy;
        float pw = (float)::exp((double)dw) * w;
        float ph = (float)::exp((double)dh) * h;
        float* bb = boxes + ((size_t)b * N + n) * 4;
        bb[0] = px - 0.5f * pw;
        bb[1] = py - 0.5f * ph;
        bb[2] = px + 0.5f * (pw - 2.0f);
        bb[3] = py + 0.5f * (ph - 2.0f);
        unsigned int sb = __float_as_uint(scores[(size_t)b * N + n]);
        kb[n] = ((u64)(~sb) << 32) | (u64)(unsigned int)n;
    } else {
        kb[n] = ~0ULL;
    }
}

// ---------------------------------------------------------------------------
// Hybrid bitonic sort (unchanged).
// ---------------------------------------------------------------------------
__global__ __launch_bounds__(1024) void bitonic_local_sort(u64* __restrict__ keys) {
    __shared__ u64 sk[TILE];
    int tile = blockIdx.x;
    u64* kb = keys + (size_t)tile * TILE;
    int base = (tile % NTILE) * TILE;
    for (int i = threadIdx.x; i < TILE; i += 1024) sk[i] = kb[i];
    __syncthreads();
    for (int k = 2; k <= TILE; k <<= 1) {
        for (int j = k >> 1; j > 0; j >>= 1) {
            for (int t = threadIdx.x; t < TILE / 2; t += 1024) {
                int i = ((t & ~(j - 1)) << 1) | (t & (j - 1));
                int ixj = i | j;
                u64 a = sk[i];
                u64 c = sk[ixj];
                bool up = (((base + i) & k) == 0);
                if ((a > c) == up) { sk[i] = c; sk[ixj] = a; }
            }
            __syncthreads();
        }
    }
    for (int i = threadIdx.x; i < TILE; i += 1024) kb[i] = sk[i];
}

__global__ void bitonic_global_step(u64* __restrict__ keys, int k, int j) {
    int t = blockIdx.x * blockDim.x + threadIdx.x;
    int b = t / (SORTN / 2);
    int s = t % (SORTN / 2);
    int i = ((s & ~(j - 1)) << 1) | (s & (j - 1));
    int ixj = i | j;
    u64* kb = keys + (size_t)b * SORTN;
    u64 a = kb[i];
    u64 c = kb[ixj];
    bool up = ((i & k) == 0);
    if ((a > c) == up) { kb[i] = c; kb[ixj] = a; }
}

__global__ __launch_bounds__(1024) void bitonic_local_merge(u64* __restrict__ keys, int k) {
    __shared__ u64 sk[TILE];
    int tile = blockIdx.x;
    u64* kb = keys + (size_t)tile * TILE;
    int base = (tile % NTILE) * TILE;
    bool up = ((base & k) == 0);
    for (int i = threadIdx.x; i < TILE; i += 1024) sk[i] = kb[i];
    __syncthreads();
    for (int j = TILE / 2; j > 0; j >>= 1) {
        for (int t = threadIdx.x; t < TILE / 2; t += 1024) {
            int i = ((t & ~(j - 1)) << 1) | (t & (j - 1));
            int ixj = i | j;
            u64 a = sk[i];
            u64 c = sk[ixj];
            if ((a > c) == up) { sk[i] = c; sk[ixj] = a; }
        }
        __syncthreads();
    }
    for (int i = threadIdx.x; i < TILE; i += 1024) kb[i] = sk[i];
}

// ---------------------------------------------------------------------------
// Gather sorted top-PADN boxes. Pad rows get far-away degenerate boxes.
// ---------------------------------------------------------------------------
__global__ void gather_sorted(const float* __restrict__ boxes,
                              const u64* __restrict__ keys,
                              float4* __restrict__ sbox, int N) {
    int r = blockIdx.x * 256 + threadIdx.x;
    int b = blockIdx.y;
    if (r >= PADN) return;
    float4 v;
    if (r < PRE_TOPN) {
        u64 key = keys[(size_t)b * SORTN + r];
        int n = (int)(unsigned)(key & 0xffffffffULL);
        v = ((const float4*)boxes)[(size_t)b * N + n];
    } else {
        v = make_float4(-4e8f, -4e8f, -4e8f, -4e8f);
    }
    sbox[(size_t)b * PADN + r] = v;
}

// ---------------------------------------------------------------------------
// Build suppression bitmap, 4 ROWS PER THREAD: 64 column boxes staged in LDS
// are amortized over 4 row computations (LDS bytes/pair 20 -> 5; round-6 was
// ~168 us of LDS-pipe time at 20 B/pair) and the 4 independent rows give ILP
// in the fully-unrolled j-loop. Plain cached stores (round-7's agent-scope
// atomic stores + per-block threadfence cost ~330 us — reverted).
// Predicate is division-free and bit-exact vs the reference:
//   RN_f32(inter/un) > 0.7f  <=>  (double)inter >= MD*(double)un,
//   MD = 0.7f + 2^-25 (25-bit x 24-bit product is exact in f64).
// Grid: (cb, 12 chunks of 1024 rows, B); early-exit if 16*chunk > cb.
// Loads clamp r to PADN-1; stores use the UNCLAMPED r so clamped duplicates
// never write (store condition r < (cb+1)*64 <= PADN).
// ---------------------------------------------------------------------------
__global__ __launch_bounds__(256) void build_bitmap(const float4* __restrict__ sbox,
                                                    u64* __restrict__ bitmap) {
#pragma clang fp contract(off)
    const double MD = (double)0.7f + 0x1p-25;   // exact midpoint multiplier
    int cb = blockIdx.x;        // column block 0..NBLK-1
    int chunk = blockIdx.y;     // row chunk (1024 rows) 0..11
    int b = blockIdx.z;
    if (16 * chunk > cb) return;  // chunk's first row >= (cb+1)*64 -> empty
    int tid = threadIdx.x;

    __shared__ float4 cbox[64];
    __shared__ float carea[64];
    const float4* sb = sbox + (size_t)b * PADN;
    if (tid < 64) {
        float4 c4 = sb[cb * 64 + tid];
        cbox[tid] = c4;
        carea[tid] = ((c4.z - c4.x) + 1.0f) * ((c4.w - c4.y) + 1.0f);
    }
    int r0 = chunk * 1024 + tid;          // rows r0, r0+256, r0+512, r0+768
    int rc0 = min(r0,       PADN - 1);
    int rc1 = min(r0 + 256, PADN - 1);
    int rc2 = min(r0 + 512, PADN - 1);
    int rc3 = min(r0 + 768, PADN - 1);
    float4 me0 = sb[rc0];
    float4 me1 = sb[rc1];
    float4 me2 = sb[rc2];
    float4 me3 = sb[rc3];
    float ar0 = ((me0.z - me0.x) + 1.0f) * ((me0.w - me0.y) + 1.0f);
    float ar1 = ((me1.z - me1.x) + 1.0f) * ((me1.w - me1.y) + 1.0f);
    float ar2 = ((me2.z - me2.x) + 1.0f) * ((me2.w - me2.y) + 1.0f);
    float ar3 = ((me3.z - me3.x) + 1.0f) * ((me3.w - me3.y) + 1.0f);
    __syncthreads();

    u64 w0 = 0, w1 = 0, w2 = 0, w3 = 0;
#pragma unroll
    for (int j = 0; j < 64; ++j) {
        float4 cj = cbox[j];
        float aj = carea[j];
        {
            float xx1 = fmaxf(me0.x, cj.x);
            float yy1 = fmaxf(me0.y, cj.y);
            float xx2 = fminf(me0.z, cj.z);
            float yy2 = fminf(me0.w, cj.w);
            float w = fmaxf((xx2 - xx1) + 1.0f, 0.0f);
            float h = fmaxf((yy2 - yy1) + 1.0f, 0.0f);
            float inter = w * h;
            float un = (ar0 + aj) - inter;
            w0 |= ((u64)((double)inter >= MD * (double)un)) << j;
        }
        {
            float xx1 = fmaxf(me1.x, cj.x);
            float yy1 = fmaxf(me1.y, cj.y);
            float xx2 = fminf(me1.z, cj.z);
            float yy2 = fminf(me1.w, cj.w);
            float w = fmaxf((xx2 - xx1) + 1.0f, 0.0f);
            float h = fmaxf((yy2 - yy1) + 1.0f, 0.0f);
            float inter = w * h;
            float un = (ar1 + aj) - inter;
            w1 |= ((u64)((double)inter >= MD * (double)un)) << j;
        }
        {
            float xx1 = fmaxf(me2.x, cj.x);
            float yy1 = fmaxf(me2.y, cj.y);
            float xx2 = fminf(me2.z, cj.z);
            float yy2 = fminf(me2.w, cj.w);
            float w = fmaxf((xx2 - xx1) + 1.0f, 0.0f);
            float h = fmaxf((yy2 - yy1) + 1.0f, 0.0f);
            float inter = w * h;
            float un = (ar2 + aj) - inter;
            w2 |= ((u64)((double)inter >= MD * (double)un)) << j;
        }
        {
            float xx1 = fmaxf(me3.x, cj.x);
            float yy1 = fmaxf(me3.y, cj.y);
            float xx2 = fminf(me3.z, cj.z);
            float yy2 = fminf(me3.w, cj.w);
            float w = fmaxf((xx2 - xx1) + 1.0f, 0.0f);
            float h = fmaxf((yy2 - yy1) + 1.0f, 0.0f);
            float inter = w * h;
            float un = (ar3 + aj) - inter;
            w3 |= ((u64)((double)inter >= MD * (double)un)) << j;
        }
    }

    // upper-triangle mask (only one of the 4 rows can hit the diagonal block)
    int cbase = cb * 64;
    int d0 = r0 - cbase;
    int d1 = r0 + 256 - cbase;
    int d2 = r0 + 512 - cbase;
    int d3 = r0 + 768 - cbase;
    if (d0 >= 0 && d0 < 64) w0 &= ~((2ULL << d0) - 1ULL);
    if (d1 >= 0 && d1 < 64) w1 &= ~((2ULL << d1) - 1ULL);
    if (d2 >= 0 && d2 < 64) w2 &= ~((2ULL << d2) - 1ULL);
    if (d3 >= 0 && d3 < 64) w3 &= ~((2ULL << d3) - 1ULL);

    int lim = (cb + 1) * 64;
    u64* dst = bitmap + (size_t)b * TRI_WORDS + (size_t)32 * cb * (cb + 1);
    if (r0       < lim) dst[r0]       = w0;
    if (r0 + 256 < lim) dst[r0 + 256] = w1;
    if (r0 + 512 < lim) dst[r0 + 512] = w2;
    if (r0 + 768 < lim) dst[r0 + 768] = w3;
}

// ---------------------------------------------------------------------------
// Sequential scan, deferred-OR (round-6 version, plain cached loads).
// ---------------------------------------------------------------------------
__global__ __launch_bounds__(256) void scan_nms(const float4* __restrict__ sbox,
                                                const u64* __restrict__ bitmap,
                                                float* __restrict__ out) {
    int b = blockIdx.x;
    int tid = threadIdx.x;
    int lane = tid & 63;
    int wv = tid >> 6;
    __shared__ int picks_lds[POST_TOPN];   // 8 KB
    __shared__ u64 s_partial[4];
    __shared__ int s_K;

    if (tid == 0) s_K = 0;
    __syncthreads();

    const u64* bm = bitmap + (size_t)b * TRI_WORDS;

    for (int rb = 0; rb < NBLK; ++rb) {
        int K = s_K;                       // uniform (post-barrier)
        if (K >= POST_TOPN) break;
        const u64* slab = bm + (size_t)32 * rb * (rb + 1);  // rows 0..(rb+1)*64-1
        int base = rb * 64;

        // wave-0 prefetch (issues before the gather's waits)
        u64 myrow = 0;
        float4 mybox = make_float4(0.f, 0.f, 0.f, 0.f);
        if (wv == 0) {
            myrow = slab[base + lane];
            mybox = sbox[(size_t)b * PADN + base + lane];
        }

        // deferred gather: OR suppression words of all prior picks
        u64 sup = 0;
        {
            int t = tid;
            for (; t + 768 < K; t += 1024) {
                u64 g0 = slab[picks_lds[t]];
                u64 g1 = slab[picks_lds[t + 256]];
                u64 g2 = slab[picks_lds[t + 512]];
                u64 g3 = slab[picks_lds[t + 768]];
                sup |= (g0 | g1) | (g2 | g3);
            }
            for (; t < K; t += 256) sup |= slab[picks_lds[t]];
        }
        for (int off = 1; off < 64; off <<= 1) sup |= shfl_xor_u64(sup, off);
        if (lane == 0) s_partial[wv] = sup;
        __syncthreads();

        if (wv == 0) {
            u64 total = s_partial[0] | s_partial[1] | s_partial[2] | s_partial[3];
            if (rb == NBLK - 1) total |= 0xFFFFFFFF00000000ULL;   // pad rows >= 12000
            int c = lane;
            u64 alive = ~total;
            u64 picks = 0;
            u64 cur = alive;
            while (cur) {
                int i = __ffsll((long long)cur) - 1;
                picks |= 1ULL << i;
                u64 row = shfl_u64(myrow, i);
                alive &= ~row;
                cur = alive & ~((2ULL << i) - 1ULL);
            }
            int avail = POST_TOPN - K;
            int np = __popcll(picks);
            while (np > avail) {                       // truncate latest picks
                picks &= ~(1ULL << (63 - __clzll(picks)));
                --np;
            }
            if ((picks >> c) & 1ULL) {
                int rank = __popcll(picks & ((1ULL << c) - 1ULL));
                picks_lds[K + rank] = base + c;
                float* o = out + ((size_t)b * POST_TOPN + K + rank) * 5;
                o[0] = (float)b; o[1] = mybox.x; o[2] = mybox.y; o[3] = mybox.z; o[4] = mybox.w;
            }
            if (c == 0) s_K = K + np;
        }
        __syncthreads();
    }

    int K = s_K;
    for (int r = K + tid; r < POST_TOPN; r += 256) {
        float* o = out + ((size_t)b * POST_TOPN + r) * 5;
        o[0] = 0.0f; o[1] = 0.0f; o[2] = 0.0f; o[3] = 0.0f; o[4] = 0.0f;
    }
}

// ---------------------------------------------------------------------------
// Fallback (round-2) NMS kernel — used only if ws_size can't hold the bitmap.
// ---------------------------------------------------------------------------
__global__ __launch_bounds__(1024) void nms_kernel(const float* __restrict__ boxes,
                                                   const u64* __restrict__ keys,
                                                   float* __restrict__ out,
                                                   int N) {
#pragma clang fp contract(off)
    __shared__ float4 kbox[POST_TOPN];
    __shared__ float kar[POST_TOPN];
    __shared__ float4 cbox[64];
    __shared__ float car_s[64];
    __shared__ int supp[64];
    __shared__ int s_cnt;

    int b = blockIdx.x;
    int tid = threadIdx.x;
    const u64* kb = keys + (size_t)b * SORTN;
    const float* bb = boxes + (size_t)b * N * 4;

    if (tid == 0) s_cnt = 0;
    __syncthreads();

    for (int start = 0; start < PRE_TOPN; start += 64) {
        int K = s_cnt;
        if (K >= POST_TOPN) break;
        int csize = min(64, PRE_TOPN - start);

        if (tid < 64) {
            int c = tid;
            if (c < csize) {
                u64 key = kb[start + c];
                int n = (int)(unsigned int)(key & 0xFFFFFFFFULL);
                const float* p = bb + (size_t)n * 4;
                float x1 = p[0], y1 = p[1], x2 = p[2], y2 = p[3];
                cbox[c] = make_float4(x1, y1, x2, y2);
                car_s[c] = ((x2 - x1) + 1.0f) * ((y2 - y1) + 1.0f);
            }
            supp[c] = 0;
        }
        __syncthreads();

        {
            int c = tid & 63;
            int sl = tid >> 6;
            if (c < csize) {
                float4 me = cbox[c];
                float ar = car_s[c];
                int flag = 0;
                for (int kk = sl; kk < K; kk += 16) {
                    float4 k0 = kbox[kk];
                    float a0 = kar[kk];
                    float xx1 = fmaxf(k0.x, me.x);
                    float yy1 = fmaxf(k0.y, me.y);
                    float xx2 = fminf(k0.z, me.z);
                    float yy2 = fminf(k0.w, me.w);
                    float w0 = fmaxf((xx2 - xx1) + 1.0f, 0.0f);
                    float h0 = fmaxf((yy2 - yy1) + 1.0f, 0.0f);
                    float inter0 = w0 * h0;
                    float iou0 = inter0 / ((a0 + ar) - inter0);
                    if (iou0 > 0.7f) { flag = 1; break; }
                }
                if (flag) supp[c] = 1;
            }
        }
        __syncthreads();

        if (tid < 64) {
            int c = tid;
            bool alive = (c < csize) && (supp[c] == 0);
            float4 me = cbox[c];
            float ar = car_s[c];
            int cnt = K;
            u64 m = __ballot(alive);
            while (m != 0 && cnt < POST_TOPN) {
                int i = __ffsll((unsigned long long)m) - 1;
                float ix1 = __shfl(me.x, i);
                float iy1 = __shfl(me.y, i);
                float ix2 = __shfl(me.z, i);
                float iy2 = __shfl(me.w, i);
                float iar = __shfl(ar, i);
                if (c == i) {
                    kbox[cnt] = me;
                    kar[cnt] = ar;
                    float* o = out + ((size_t)b * POST_TOPN + cnt) * 5;
                    o[0] = (float)b; o[1] = me.x; o[2] = me.y; o[3] = me.z; o[4] = me.w;
                }
                if (alive && c > i) {
                    float xx1 = fmaxf(ix1, me.x);
                    float yy1 = fmaxf(iy1, me.y);
                    float xx2 = fminf(ix2, me.z);
                    float yy2 = fminf(iy2, me.w);
                    float w = fmaxf((xx2 - xx1) + 1.0f, 0.0f);
                    float h = fmaxf((yy2 - yy1) + 1.0f, 0.0f);
                    float inter = w * h;
                    float iou = inter / ((iar + ar) - inter);
                    if (iou > 0.7f) alive = false;
                }
                cnt++;
                m = __ballot(alive);
                u64 clearmask = (2ULL << i) - 1ULL;
                m &= ~clearmask;
            }
            if (c == 0) s_cnt = cnt;
        }
        __syncthreads();
    }

    __syncthreads();
    int K = s_cnt;
    for (int r = K + tid; r < POST_TOPN; r += (int)blockDim.x) {
        float* o = out + ((size_t)b * POST_TOPN + r) * 5;
        o[0] = 0.0f; o[1] = 0.0f; o[2] = 0.0f; o[3] = 0.0f; o[4] = 0.0f;
    }
}

// ---------------------------------------------------------------------------
extern "C" void kernel_launch(void* const* d_in, const int* in_sizes, int n_in,
                              void* d_out, int out_size, void* d_ws, size_t ws_size,
                              hipStream_t stream) {
    const float* anchors = (const float*)d_in[0];
    const float* deltas  = (const float*)d_in[1];
    const float* scores  = (const float*)d_in[2];
    float* out = (float*)d_out;

    int N = in_sizes[0] / 4;           // 27380
    int B = in_sizes[2] / N;           // 8

    size_t off = 0;
    auto take = [&](size_t bytes) { size_t o = off; off = (off + bytes + 255) & ~(size_t)255; return o; };
    size_t boxesOff  = take((size_t)B * N * 4 * sizeof(float));
    size_t keysOff   = take((size_t)B * SORTN * sizeof(u64));
    size_t sboxOff   = take((size_t)B * PADN * sizeof(float4));
    size_t bitmapOff = take((size_t)B * TRI_WORDS * sizeof(u64));
    bool bitmap_path = (off <= ws_size);

    float* boxes = (float*)((char*)d_ws + boxesOff);
    u64*   keys  = (u64*)((char*)d_ws + keysOff);

    dim3 g1((unsigned)((SORTN + 255) / 256), (unsigned)B);
    decode_pack<<<g1, 256, 0, stream>>>(anchors, deltas, scores, boxes, keys, N);

    int ntiles = B * NTILE;
    bitonic_local_sort<<<ntiles, 1024, 0, stream>>>(keys);
    int gsteps = B * (SORTN / 2) / 256;
    bitonic_global_step<<<gsteps, 256, 0, stream>>>(keys, 2 * TILE, TILE);
    bitonic_local_merge<<<ntiles, 1024, 0, stream>>>(keys, 2 * TILE);
    bitonic_global_step<<<gsteps, 256, 0, stream>>>(keys, 4 * TILE, 2 * TILE);
    bitonic_global_step<<<gsteps, 256, 0, stream>>>(keys, 4 * TILE, TILE);
    bitonic_local_merge<<<ntiles, 1024, 0, stream>>>(keys, 4 * TILE);

    if (bitmap_path) {
        float4* sbox = (float4*)((char*)d_ws + sboxOff);
        u64* bitmap  = (u64*)((char*)d_ws + bitmapOff);
        dim3 gg((unsigned)((PADN + 255) / 256), (unsigned)B);
        gather_sorted<<<gg, 256, 0, stream>>>(boxes, keys, sbox, N);
        dim3 gb((unsigned)NBLK, 12u, (unsigned)B);
        build_bitmap<<<gb, 256, 0, stream>>>(sbox, bitmap);
        scan_nms<<<B, 256, 0, stream>>>(sbox, bitmap, out);
    } else {
        nms_kernel<<<B, 1024, 0, stream>>>(boxes, keys, out, N);
    }
}

// Round 10
// 819.650 us; speedup vs baseline: 1.1262x; 1.0271x over previous
//
#include <hip/hip_runtime.h>
#include <cmath>

typedef unsigned long long u64;

#define PRE_TOPN 12000
#define POST_TOPN 2000
#define SORTN 32768
#define TILE 8192
#define NTILE (SORTN / TILE)   // 4 tiles per batch
#define NBLK 188               // 64-bit column blocks covering 12032
#define PADN (NBLK * 64)       // 12032
// triangular bitmap: column-block cb stores rows 0..(cb+1)*64-1
// triOff(cb) = 32*cb*(cb+1); total words per batch:
#define TRI_WORDS (32 * (NBLK - 1) * NBLK + NBLK * 64)  // 1,137,024

__device__ inline u64 shfl_u64(u64 v, int lane) {
    int lo = __shfl((int)(unsigned)(v & 0xffffffffULL), lane);
    int hi = __shfl((int)(unsigned)(v >> 32), lane);
    return ((u64)(unsigned)hi << 32) | (u64)(unsigned)lo;
}

__device__ inline u64 shfl_xor_u64(u64 v, int mask) {
    int lo = __shfl_xor((int)(unsigned)(v & 0xffffffffULL), mask);
    int hi = __shfl_xor((int)(unsigned)(v >> 32), mask);
    return ((u64)(unsigned)hi << 32) | (u64)(unsigned)lo;
}

// ---------------------------------------------------------------------------
// Kernel 1: decode boxes (exact fp32 op order, no FMA contraction, exp via
// double) and pack sort keys. key = (~score_bits)<<32 | idx.
// ---------------------------------------------------------------------------
__global__ void decode_pack(const float* __restrict__ anchors,
                            const float* __restrict__ deltas,
                            const float* __restrict__ scores,
                            float* __restrict__ boxes,
                            u64* __restrict__ keys,
                            int N) {
#pragma clang fp contract(off)
    int n = blockIdx.x * blockDim.x + threadIdx.x;
    int b = blockIdx.y;
    if (n >= SORTN) return;
    u64* kb = keys + (size_t)b * SORTN;
    if (n < N) {
        float a0 = anchors[n * 4 + 0];
        float a1 = anchors[n * 4 + 1];
        float a2 = anchors[n * 4 + 2];
        float a3 = anchors[n * 4 + 3];
        float w = (a2 - a0) + 1.0f;
        float h = (a3 - a1) + 1.0f;
        float cx = a0 + 0.5f * w;
        float cy = a1 + 0.5f * h;
        const float* d = deltas + ((size_t)b * N + n) * 4;
        float dx = d[0], dy = d[1], dw = d[2], dh = d[3];
        float px = cx + w * dx;
        float py = cy + h * dy;
        float pw = (float)::exp((double)dw) * w;
        float ph = (float)::exp((double)dh) * h;
        float* bb = boxes + ((size_t)b * N + n) * 4;
        bb[0] = px - 0.5f * pw;
        bb[1] = py - 0.5f * ph;
        bb[2] = px + 0.5f * (pw - 2.0f);
        bb[3] = py + 0.5f * (ph - 2.0f);
        unsigned int sb = __float_as_uint(scores[(size_t)b * N + n]);
        kb[n] = ((u64)(~sb) << 32) | (u64)(unsigned int)n;
    } else {
        kb[n] = ~0ULL;
    }
}

// ---------------------------------------------------------------------------
// Hybrid bitonic sort (unchanged).
// ---------------------------------------------------------------------------
__global__ __launch_bounds__(1024) void bitonic_local_sort(u64* __restrict__ keys) {
    __shared__ u64 sk[TILE];
    int tile = blockIdx.x;
    u64* kb = keys + (size_t)tile * TILE;
    int base = (tile % NTILE) * TILE;
    for (int i = threadIdx.x; i < TILE; i += 1024) sk[i] = kb[i];
    __syncthreads();
    for (int k = 2; k <= TILE; k <<= 1) {
        for (int j = k >> 1; j > 0; j >>= 1) {
            for (int t = threadIdx.x; t < TILE / 2; t += 1024) {
                int i = ((t & ~(j - 1)) << 1) | (t & (j - 1));
                int ixj = i | j;
                u64 a = sk[i];
                u64 c = sk[ixj];
                bool up = (((base + i) & k) == 0);
                if ((a > c) == up) { sk[i] = c; sk[ixj] = a; }
            }
            __syncthreads();
        }
    }
    for (int i = threadIdx.x; i < TILE; i += 1024) kb[i] = sk[i];
}

__global__ void bitonic_global_step(u64* __restrict__ keys, int k, int j) {
    int t = blockIdx.x * blockDim.x + threadIdx.x;
    int b = t / (SORTN / 2);
    int s = t % (SORTN / 2);
    int i = ((s & ~(j - 1)) << 1) | (s & (j - 1));
    int ixj = i | j;
    u64* kb = keys + (size_t)b * SORTN;
    u64 a = kb[i];
    u64 c = kb[ixj];
    bool up = ((i & k) == 0);
    if ((a > c) == up) { kb[i] = c; kb[ixj] = a; }
}

__global__ __launch_bounds__(1024) void bitonic_local_merge(u64* __restrict__ keys, int k) {
    __shared__ u64 sk[TILE];
    int tile = blockIdx.x;
    u64* kb = keys + (size_t)tile * TILE;
    int base = (tile % NTILE) * TILE;
    bool up = ((base & k) == 0);
    for (int i = threadIdx.x; i < TILE; i += 1024) sk[i] = kb[i];
    __syncthreads();
    for (int j = TILE / 2; j > 0; j >>= 1) {
        for (int t = threadIdx.x; t < TILE / 2; t += 1024) {
            int i = ((t & ~(j - 1)) << 1) | (t & (j - 1));
            int ixj = i | j;
            u64 a = sk[i];
            u64 c = sk[ixj];
            if ((a > c) == up) { sk[i] = c; sk[ixj] = a; }
        }
        __syncthreads();
    }
    for (int i = threadIdx.x; i < TILE; i += 1024) kb[i] = sk[i];
}

// ---------------------------------------------------------------------------
// Gather sorted top-PADN boxes. Pad rows get far-away degenerate boxes.
// ---------------------------------------------------------------------------
__global__ void gather_sorted(const float* __restrict__ boxes,
                              const u64* __restrict__ keys,
                              float4* __restrict__ sbox, int N) {
    int r = blockIdx.x * 256 + threadIdx.x;
    int b = blockIdx.y;
    if (r >= PADN) return;
    float4 v;
    if (r < PRE_TOPN) {
        u64 key = keys[(size_t)b * SORTN + r];
        int n = (int)(unsigned)(key & 0xffffffffULL);
        v = ((const float4*)boxes)[(size_t)b * N + n];
    } else {
        v = make_float4(-4e8f, -4e8f, -4e8f, -4e8f);
    }
    sbox[(size_t)b * PADN + r] = v;
}

// ---------------------------------------------------------------------------
// Build suppression bitmap — LDS-free, readlane-broadcast, LANE = ROW.
//   Each wave owns 64 rows; lane L holds row (rowbase+L)'s box AND column
//   (cb*64+L)'s box in VGPRs (both coalesced global loads). The fully-
//   unrolled inner loop broadcasts column j via 5 v_readlane (VALU pipe,
//   immediate lane index — no LDS, no barriers, no writelane/ballot);
//   each lane computes IoU(its row, col j) and ORs bit j into a private
//   32+32-bit word with a constant shift. Lane L then stores row
//   rowbase+L's word — coalesced.
//   Round-6 (LDS-staged) stalled on lgkmcnt with a 36-VGPR window (~50%
//   issue eff); round-8 (4 rows/thread) blew VGPRs (184, 11% occupancy).
//   This version: ~30 VGPRs, pure VALU stream (~24 inst/64 pairs).
// Predicate (division-free, bit-exact vs reference, validated r5-r8):
//   RN_f32(inter/un) > 0.7f  <=>  (double)inter >= MD*(double)un,
//   MD = 0.7f + 2^-25 (25-bit x 24-bit product exact in f64).
// Grid (cb, 47 chunks of 256 rows, B); block-level triangular early-exit,
// wave-uniform exit if rowbase >= (cb+1)*64. Entered waves have all 64 rows
// < (cb+1)*64 (rowbase multiple of 64, <= cb*64) -> unconditional stores;
// the diagonal wave is rowbase == cb*64 (d = lane in [0,63]).
// ---------------------------------------------------------------------------
__global__ __launch_bounds__(256) void build_bitmap(const float4* __restrict__ sbox,
                                                    u64* __restrict__ bitmap) {
#pragma clang fp contract(off)
    const double MD = (double)0.7f + 0x1p-25;   // exact midpoint multiplier
    int cb = blockIdx.x;        // column block 0..NBLK-1
    int chunk = blockIdx.y;     // row chunk (256 rows) 0..46
    int b = blockIdx.z;
    if (chunk * 4 > cb) return; // chunk's first row >= (cb+1)*64 -> empty
    int tid = threadIdx.x;
    int lane = tid & 63;
    int wv = tid >> 6;
    int rowbase = chunk * 256 + wv * 64;
    if (rowbase >= (cb + 1) * 64) return;   // wave-uniform exit

    const float4* sb = sbox + (size_t)b * PADN;
    float4 c4 = sb[cb * 64 + lane];                       // lane L holds column cb*64+L
    float ca = ((c4.z - c4.x) + 1.0f) * ((c4.w - c4.y) + 1.0f);
    float4 r4 = sb[rowbase + lane];                       // lane L holds row rowbase+L
    float ra = ((r4.z - r4.x) + 1.0f) * ((r4.w - r4.y) + 1.0f);

    unsigned wlo = 0, whi = 0;
#pragma unroll
    for (int j = 0; j < 64; ++j) {
        float cx1 = __uint_as_float(__builtin_amdgcn_readlane(__float_as_uint(c4.x), j));
        float cy1 = __uint_as_float(__builtin_amdgcn_readlane(__float_as_uint(c4.y), j));
        float cx2 = __uint_as_float(__builtin_amdgcn_readlane(__float_as_uint(c4.z), j));
        float cy2 = __uint_as_float(__builtin_amdgcn_readlane(__float_as_uint(c4.w), j));
        float caj = __uint_as_float(__builtin_amdgcn_readlane(__float_as_uint(ca), j));
        float xx1 = fmaxf(r4.x, cx1);
        float yy1 = fmaxf(r4.y, cy1);
        float xx2 = fminf(r4.z, cx2);
        float yy2 = fminf(r4.w, cy2);
        float w = fmaxf((xx2 - xx1) + 1.0f, 0.0f);
        float h = fmaxf((yy2 - yy1) + 1.0f, 0.0f);
        float inter = w * h;
        float un = (ra + caj) - inter;
        bool sup = ((double)inter >= MD * (double)un);
        if (j < 32) wlo |= ((unsigned)sup) << j;
        else        whi |= ((unsigned)sup) << (j - 32);
    }

    int r = rowbase + lane;
    u64 w64 = ((u64)whi << 32) | (u64)wlo;
    int d = r - cb * 64;                     // in [0,63] only for diagonal wave
    if (d >= 0 && d < 64) w64 &= ~((2ULL << d) - 1ULL);   // upper triangle only
    bitmap[(size_t)b * TRI_WORDS + (size_t)32 * cb * (cb + 1) + (size_t)r] = w64;
}

// ---------------------------------------------------------------------------
// Sequential scan, deferred-OR (round-6 version, plain cached loads).
// ---------------------------------------------------------------------------
__global__ __launch_bounds__(256) void scan_nms(const float4* __restrict__ sbox,
                                                const u64* __restrict__ bitmap,
                                                float* __restrict__ out) {
    int b = blockIdx.x;
    int tid = threadIdx.x;
    int lane = tid & 63;
    int wv = tid >> 6;
    __shared__ int picks_lds[POST_TOPN];   // 8 KB
    __shared__ u64 s_partial[4];
    __shared__ int s_K;

    if (tid == 0) s_K = 0;
    __syncthreads();

    const u64* bm = bitmap + (size_t)b * TRI_WORDS;

    for (int rb = 0; rb < NBLK; ++rb) {
        int K = s_K;                       // uniform (post-barrier)
        if (K >= POST_TOPN) break;
        const u64* slab = bm + (size_t)32 * rb * (rb + 1);  // rows 0..(rb+1)*64-1
        int base = rb * 64;

        // wave-0 prefetch (issues before the gather's waits)
        u64 myrow = 0;
        float4 mybox = make_float4(0.f, 0.f, 0.f, 0.f);
        if (wv == 0) {
            myrow = slab[base + lane];
            mybox = sbox[(size_t)b * PADN + base + lane];
        }

        // deferred gather: OR suppression words of all prior picks
        u64 sup = 0;
        {
            int t = tid;
            for (; t + 768 < K; t += 1024) {
                u64 g0 = slab[picks_lds[t]];
                u64 g1 = slab[picks_lds[t + 256]];
                u64 g2 = slab[picks_lds[t + 512]];
                u64 g3 = slab[picks_lds[t + 768]];
                sup |= (g0 | g1) | (g2 | g3);
            }
            for (; t < K; t += 256) sup |= slab[picks_lds[t]];
        }
        for (int off = 1; off < 64; off <<= 1) sup |= shfl_xor_u64(sup, off);
        if (lane == 0) s_partial[wv] = sup;
        __syncthreads();

        if (wv == 0) {
            u64 total = s_partial[0] | s_partial[1] | s_partial[2] | s_partial[3];
            if (rb == NBLK - 1) total |= 0xFFFFFFFF00000000ULL;   // pad rows >= 12000
            int c = lane;
            u64 alive = ~total;
            u64 picks = 0;
            u64 cur = alive;
            while (cur) {
                int i = __ffsll((long long)cur) - 1;
                picks |= 1ULL << i;
                u64 row = shfl_u64(myrow, i);
                alive &= ~row;
                cur = alive & ~((2ULL << i) - 1ULL);
            }
            int avail = POST_TOPN - K;
            int np = __popcll(picks);
            while (np > avail) {                       // truncate latest picks
                picks &= ~(1ULL << (63 - __clzll(picks)));
                --np;
            }
            if ((picks >> c) & 1ULL) {
                int rank = __popcll(picks & ((1ULL << c) - 1ULL));
                picks_lds[K + rank] = base + c;
                float* o = out + ((size_t)b * POST_TOPN + K + rank) * 5;
                o[0] = (float)b; o[1] = mybox.x; o[2] = mybox.y; o[3] = mybox.z; o[4] = mybox.w;
            }
            if (c == 0) s_K = K + np;
        }
        __syncthreads();
    }

    int K = s_K;
    for (int r = K + tid; r < POST_TOPN; r += 256) {
        float* o = out + ((size_t)b * POST_TOPN + r) * 5;
        o[0] = 0.0f; o[1] = 0.0f; o[2] = 0.0f; o[3] = 0.0f; o[4] = 0.0f;
    }
}

// ---------------------------------------------------------------------------
// Fallback (round-2) NMS kernel — used only if ws_size can't hold the bitmap.
// ---------------------------------------------------------------------------
__global__ __launch_bounds__(1024) void nms_kernel(const float* __restrict__ boxes,
                                                   const u64* __restrict__ keys,
                                                   float* __restrict__ out,
                                                   int N) {
#pragma clang fp contract(off)
    __shared__ float4 kbox[POST_TOPN];
    __shared__ float kar[POST_TOPN];
    __shared__ float4 cbox[64];
    __shared__ float car_s[64];
    __shared__ int supp[64];
    __shared__ int s_cnt;

    int b = blockIdx.x;
    int tid = threadIdx.x;
    const u64* kb = keys + (size_t)b * SORTN;
    const float* bb = boxes + (size_t)b * N * 4;

    if (tid == 0) s_cnt = 0;
    __syncthreads();

    for (int start = 0; start < PRE_TOPN; start += 64) {
        int K = s_cnt;
        if (K >= POST_TOPN) break;
        int csize = min(64, PRE_TOPN - start);

        if (tid < 64) {
            int c = tid;
            if (c < csize) {
                u64 key = kb[start + c];
                int n = (int)(unsigned int)(key & 0xFFFFFFFFULL);
                const float* p = bb + (size_t)n * 4;
                float x1 = p[0], y1 = p[1], x2 = p[2], y2 = p[3];
                cbox[c] = make_float4(x1, y1, x2, y2);
                car_s[c] = ((x2 - x1) + 1.0f) * ((y2 - y1) + 1.0f);
            }
            supp[c] = 0;
        }
        __syncthreads();

        {
            int c = tid & 63;
            int sl = tid >> 6;
            if (c < csize) {
                float4 me = cbox[c];
                float ar = car_s[c];
                int flag = 0;
                for (int kk = sl; kk < K; kk += 16) {
                    float4 k0 = kbox[kk];
                    float a0 = kar[kk];
                    float xx1 = fmaxf(k0.x, me.x);
                    float yy1 = fmaxf(k0.y, me.y);
                    float xx2 = fminf(k0.z, me.z);
                    float yy2 = fminf(k0.w, me.w);
                    float w0 = fmaxf((xx2 - xx1) + 1.0f, 0.0f);
                    float h0 = fmaxf((yy2 - yy1) + 1.0f, 0.0f);
                    float inter0 = w0 * h0;
                    float iou0 = inter0 / ((a0 + ar) - inter0);
                    if (iou0 > 0.7f) { flag = 1; break; }
                }
                if (flag) supp[c] = 1;
            }
        }
        __syncthreads();

        if (tid < 64) {
            int c = tid;
            bool alive = (c < csize) && (supp[c] == 0);
            float4 me = cbox[c];
            float ar = car_s[c];
            int cnt = K;
            u64 m = __ballot(alive);
            while (m != 0 && cnt < POST_TOPN) {
                int i = __ffsll((unsigned long long)m) - 1;
                float ix1 = __shfl(me.x, i);
                float iy1 = __shfl(me.y, i);
                float ix2 = __shfl(me.z, i);
                float iy2 = __shfl(me.w, i);
                float iar = __shfl(ar, i);
                if (c == i) {
                    kbox[cnt] = me;
                    kar[cnt] = ar;
                    float* o = out + ((size_t)b * POST_TOPN + cnt) * 5;
                    o[0] = (float)b; o[1] = me.x; o[2] = me.y; o[3] = me.z; o[4] = me.w;
                }
                if (alive && c > i) {
                    float xx1 = fmaxf(ix1, me.x);
                    float yy1 = fmaxf(iy1, me.y);
                    float xx2 = fminf(ix2, me.z);
                    float yy2 = fminf(iy2, me.w);
                    float w = fmaxf((xx2 - xx1) + 1.0f, 0.0f);
                    float h = fmaxf((yy2 - yy1) + 1.0f, 0.0f);
                    float inter = w * h;
                    float iou = inter / ((iar + ar) - inter);
                    if (iou > 0.7f) alive = false;
                }
                cnt++;
                m = __ballot(alive);
                u64 clearmask = (2ULL << i) - 1ULL;
                m &= ~clearmask;
            }
            if (c == 0) s_cnt = cnt;
        }
        __syncthreads();
    }

    __syncthreads();
    int K = s_cnt;
    for (int r = K + tid; r < POST_TOPN; r += (int)blockDim.x) {
        float* o = out + ((size_t)b * POST_TOPN + r) * 5;
        o[0] = 0.0f; o[1] = 0.0f; o[2] = 0.0f; o[3] = 0.0f; o[4] = 0.0f;
    }
}

// ---------------------------------------------------------------------------
extern "C" void kernel_launch(void* const* d_in, const int* in_sizes, int n_in,
                              void* d_out, int out_size, void* d_ws, size_t ws_size,
                              hipStream_t stream) {
    const float* anchors = (const float*)d_in[0];
    const float* deltas  = (const float*)d_in[1];
    const float* scores  = (const float*)d_in[2];
    float* out = (float*)d_out;

    int N = in_sizes[0] / 4;           // 27380
    int B = in_sizes[2] / N;           // 8

    size_t off = 0;
    auto take = [&](size_t bytes) { size_t o = off; off = (off + bytes + 255) & ~(size_t)255; return o; };
    size_t boxesOff  = take((size_t)B * N * 4 * sizeof(float));
    size_t keysOff   = take((size_t)B * SORTN * sizeof(u64));
    size_t sboxOff   = take((size_t)B * PADN * sizeof(float4));
    size_t bitmapOff = take((size_t)B * TRI_WORDS * sizeof(u64));
    bool bitmap_path = (off <= ws_size);

    float* boxes = (float*)((char*)d_ws + boxesOff);
    u64*   keys  = (u64*)((char*)d_ws + keysOff);

    dim3 g1((unsigned)((SORTN + 255) / 256), (unsigned)B);
    decode_pack<<<g1, 256, 0, stream>>>(anchors, deltas, scores, boxes, keys, N);

    int ntiles = B * NTILE;
    bitonic_local_sort<<<ntiles, 1024, 0, stream>>>(keys);
    int gsteps = B * (SORTN / 2) / 256;
    bitonic_global_step<<<gsteps, 256, 0, stream>>>(keys, 2 * TILE, TILE);
    bitonic_local_merge<<<ntiles, 1024, 0, stream>>>(keys, 2 * TILE);
    bitonic_global_step<<<gsteps, 256, 0, stream>>>(keys, 4 * TILE, 2 * TILE);
    bitonic_global_step<<<gsteps, 256, 0, stream>>>(keys, 4 * TILE, TILE);
    bitonic_local_merge<<<ntiles, 1024, 0, stream>>>(keys, 4 * TILE);

    if (bitmap_path) {
        float4* sbox = (float4*)((char*)d_ws + sboxOff);
        u64* bitmap  = (u64*)((char*)d_ws + bitmapOff);
        dim3 gg((unsigned)((PADN + 255) / 256), (unsigned)B);
        gather_sorted<<<gg, 256, 0, stream>>>(boxes, keys, sbox, N);
        dim3 gb((unsigned)NBLK, 47u, (unsigned)B);
        build_bitmap<<<gb, 256, 0, stream>>>(sbox, bitmap);
        scan_nms<<<B, 256, 0, stream>>>(sbox, bitmap, out);
    } else {
        nms_kernel<<<B, 1024, 0, stream>>>(boxes, keys, out, N);
    }
}